// Round 1
// baseline (259.767 us; speedup 1.0000x reference)
//
#include <hip/hip_runtime.h>

typedef short v8s __attribute__((ext_vector_type(8)));
typedef float v4f __attribute__((ext_vector_type(4)));
typedef unsigned int v2u __attribute__((ext_vector_type(2)));

#define NC 256
#define ND 128

__device__ __forceinline__ unsigned short f2bf(float f) {
  union { float f; unsigned int u; } v; v.f = f;
  unsigned int u = v.u;
  unsigned int r = (u + 0x7fffu + ((u >> 16) & 1u)) >> 16;
  return (unsigned short)r;
}

// ---------------- prep: bf16 copies of P/G, P^T, norms, gate ----------------
__global__ void som_prep_kernel(const float* __restrict__ P, const float* __restrict__ G,
                                const float* __restrict__ gate_logits,
                                unsigned short* __restrict__ Pbf, unsigned short* __restrict__ Gbf,
                                unsigned short* __restrict__ PTbf,
                                float* __restrict__ b2p, float* __restrict__ b2g,
                                float* __restrict__ gatev) {
  int c = blockIdx.x;      // 0..255
  int t = threadIdx.x;     // 0..127
  float p = P[c * ND + t];
  float g = G[c * ND + t];
  Pbf[c * ND + t] = f2bf(p);
  Gbf[c * ND + t] = f2bf(g);
  PTbf[t * NC + c] = f2bf(p);
  float pp = p * p, gg = g * g;
  #pragma unroll
  for (int m = 1; m < 64; m <<= 1) { pp += __shfl_xor(pp, m); gg += __shfl_xor(gg, m); }
  __shared__ float sp[2], sg[2];
  if ((t & 63) == 0) { sp[t >> 6] = pp; sg[t >> 6] = gg; }
  __syncthreads();
  if (t == 0) {
    b2p[c] = sp[0] + sp[1];
    b2g[c] = sg[0] + sg[1];
    gatev[c] = 1.f / (1.f + expf(-gate_logits[c]));
  }
}

// ---------------- main fused kernel ----------------
// Block: 256 threads = 4 waves. Each wave owns 32 x-rows (2 m-tiles of 16).
// S^T = P_tile(16c x 32k) * X^T(32k x 16m)  -> lane holds c-quad for its own row m=lane&15.
__global__ __launch_bounds__(256, 2) void som_main_kernel(
    const float* __restrict__ x,
    const unsigned short* __restrict__ Pbf,
    const unsigned short* __restrict__ Gbf,
    const unsigned short* __restrict__ PTbf,
    const float* __restrict__ b2p,
    const float* __restrict__ b2g,
    const float* __restrict__ gatev,
    const float* __restrict__ temp_raw,
    float* __restrict__ blended_out,
    float* __restrict__ w_out)
{
  __shared__ char smem[65536];                 // 4 waves x 16 KB (w tile, bf16, swizzled)
  const int tid  = threadIdx.x;
  const int wid  = tid >> 6;
  const int lane = tid & 63;
  const int lrow = lane & 15;                  // m within tile / row of A-frag
  const int g    = lane >> 4;                  // k-chunk selector
  const long long R = ((long long)blockIdx.x * 4 + wid) * 32;
  char* wl = smem + wid * 16384;

  float traw = temp_raw[0];
  float T = 1.f / (1.f + __expf(-traw)) * (1.f - 1e-3f) + 1e-3f;
  float invT = 1.f / T;

  // ---- X fragments (B operand of S^T) + exact f32 row norms ----
  v8s xb[2][4];
  float a2[2];
  #pragma unroll
  for (int mt = 0; mt < 2; ++mt) {
    const float* xrow = x + (R + mt * 16 + lrow) * ND + g * 8;
    float part = 0.f;
    #pragma unroll
    for (int ks = 0; ks < 4; ++ks) {
      v4f v0 = *(const v4f*)(xrow + ks * 32);
      v4f v1 = *(const v4f*)(xrow + ks * 32 + 4);
      v8s b;
      #pragma unroll
      for (int j = 0; j < 4; ++j) {
        b[j]     = (short)f2bf(v0[j]);
        b[j + 4] = (short)f2bf(v1[j]);
        part += v0[j] * v0[j] + v1[j] * v1[j];
      }
      xb[mt][ks] = b;
    }
    part += __shfl_xor(part, 16);
    part += __shfl_xor(part, 32);
    a2[mt] = part;
  }

  // ---- distances -> e = exp(-d_total/T), lane holds c = ct*16 + g*4 + r ----
  v4f e[2][16];
  #pragma unroll
  for (int ct = 0; ct < 16; ++ct) {
    v4f aP0 = {0.f,0.f,0.f,0.f}, aP1 = {0.f,0.f,0.f,0.f};
    v4f aG0 = {0.f,0.f,0.f,0.f}, aG1 = {0.f,0.f,0.f,0.f};
    const unsigned short* prow = Pbf + (ct * 16 + lrow) * ND + g * 8;
    const unsigned short* grow = Gbf + (ct * 16 + lrow) * ND + g * 8;
    #pragma unroll
    for (int ks = 0; ks < 4; ++ks) {
      v8s ap = *(const v8s*)(prow + ks * 32);
      v8s ag = *(const v8s*)(grow + ks * 32);
      aP0 = __builtin_amdgcn_mfma_f32_16x16x32_bf16(ap, xb[0][ks], aP0, 0, 0, 0);
      aP1 = __builtin_amdgcn_mfma_f32_16x16x32_bf16(ap, xb[1][ks], aP1, 0, 0, 0);
      aG0 = __builtin_amdgcn_mfma_f32_16x16x32_bf16(ag, xb[0][ks], aG0, 0, 0, 0);
      aG1 = __builtin_amdgcn_mfma_f32_16x16x32_bf16(ag, xb[1][ks], aG1, 0, 0, 0);
    }
    v4f bp = *(const v4f*)(b2p + ct * 16 + g * 4);
    v4f bg = *(const v4f*)(b2g + ct * 16 + g * 4);
    #pragma unroll
    for (int r = 0; r < 4; ++r) {
      float d0 = sqrtf(fmaxf(a2[0] + bp[r] - 2.f * aP0[r], 1e-12f))
               + sqrtf(fmaxf(a2[0] + bg[r] - 2.f * aG0[r], 1e-12f));
      float d1 = sqrtf(fmaxf(a2[1] + bp[r] - 2.f * aP1[r], 1e-12f))
               + sqrtf(fmaxf(a2[1] + bg[r] - 2.f * aG1[r], 1e-12f));
      e[0][ct][r] = __expf(-d0 * invT);
      e[1][ct][r] = __expf(-d1 * invT);
    }
  }

  // ---- double normalization with gate (exact reference semantics) ----
  float s1a = 0.f, s1b = 0.f;
  #pragma unroll
  for (int ct = 0; ct < 16; ++ct)
    #pragma unroll
    for (int r = 0; r < 4; ++r) { s1a += e[0][ct][r]; s1b += e[1][ct][r]; }
  s1a += __shfl_xor(s1a, 16); s1a += __shfl_xor(s1a, 32);
  s1b += __shfl_xor(s1b, 16); s1b += __shfl_xor(s1b, 32);
  float i1a = 1.f / (s1a + 1e-8f);
  float i1b = 1.f / (s1b + 1e-8f);

  float s2a = 0.f, s2b = 0.f;
  #pragma unroll
  for (int ct = 0; ct < 16; ++ct) {
    v4f gt = *(const v4f*)(gatev + ct * 16 + g * 4);
    #pragma unroll
    for (int r = 0; r < 4; ++r) {
      float va = e[0][ct][r] * gt[r] * i1a;
      float vb = e[1][ct][r] * gt[r] * i1b;
      e[0][ct][r] = va; e[1][ct][r] = vb;
      s2a += va; s2b += vb;
    }
  }
  s2a += __shfl_xor(s2a, 16); s2a += __shfl_xor(s2a, 32);
  s2b += __shfl_xor(s2b, 16); s2b += __shfl_xor(s2b, 32);
  float i2a = 1.f / (s2a + 1e-8f);
  float i2b = 1.f / (s2b + 1e-8f);

  // ---- write w: f32 coalesced global + bf16 swizzled LDS ----
  #pragma unroll
  for (int ct = 0; ct < 16; ++ct) {
    #pragma unroll
    for (int mt = 0; mt < 2; ++mt) {
      float i2 = mt ? i2b : i2a;
      v4f w;
      #pragma unroll
      for (int r = 0; r < 4; ++r) w[r] = e[mt][ct][r] * i2;
      *(v4f*)(w_out + (R + mt * 16 + lrow) * NC + ct * 16 + g * 4) = w;
      unsigned int lo = (unsigned int)f2bf(w[0]) | ((unsigned int)f2bf(w[1]) << 16);
      unsigned int hi = (unsigned int)f2bf(w[2]) | ((unsigned int)f2bf(w[3]) << 16);
      int row = mt * 16 + lrow;
      int u = (2 * ct + (g >> 1)) ^ row;                   // 16B-unit XOR swizzle
      char* dst = wl + row * 512 + u * 16 + (g & 1) * 8;
      v2u pk; pk[0] = lo; pk[1] = hi;
      *(v2u*)dst = pk;
    }
  }

  __syncthreads();

  // ---- blended^T = PT_tile(16d x 32c) * W^T(32c x 16m) ----
  v4f acc[8][2];
  #pragma unroll
  for (int dt = 0; dt < 8; ++dt) {
    acc[dt][0] = (v4f){0.f,0.f,0.f,0.f};
    acc[dt][1] = (v4f){0.f,0.f,0.f,0.f};
  }
  #pragma unroll
  for (int kc = 0; kc < 8; ++kc) {
    v8s wb[2];
    #pragma unroll
    for (int mt = 0; mt < 2; ++mt) {
      int row = mt * 16 + lrow;
      int u = (kc * 4 + g) ^ row;
      wb[mt] = *(const v8s*)(wl + row * 512 + u * 16);
    }
    #pragma unroll
    for (int dt = 0; dt < 8; ++dt) {
      v8s pa = *(const v8s*)(PTbf + (dt * 16 + lrow) * NC + kc * 32 + g * 8);
      acc[dt][0] = __builtin_amdgcn_mfma_f32_16x16x32_bf16(pa, wb[0], acc[dt][0], 0, 0, 0);
      acc[dt][1] = __builtin_amdgcn_mfma_f32_16x16x32_bf16(pa, wb[1], acc[dt][1], 0, 0, 0);
    }
  }
  #pragma unroll
  for (int dt = 0; dt < 8; ++dt)
    #pragma unroll
    for (int mt = 0; mt < 2; ++mt)
      *(v4f*)(blended_out + (R + mt * 16 + lrow) * ND + dt * 16 + g * 4) = acc[dt][mt];
}

extern "C" void kernel_launch(void* const* d_in, const int* in_sizes, int n_in,
                              void* d_out, int out_size, void* d_ws, size_t ws_size,
                              hipStream_t stream) {
  const float* x    = (const float*)d_in[0];
  const float* P    = (const float*)d_in[1];
  const float* G    = (const float*)d_in[2];
  const float* traw = (const float*)d_in[3];
  const float* gl   = (const float*)d_in[4];
  const int N = in_sizes[0] / ND;             // 262144

  char* ws = (char*)d_ws;
  unsigned short* Pbf  = (unsigned short*)(ws);
  unsigned short* Gbf  = (unsigned short*)(ws + 65536);
  unsigned short* PTbf = (unsigned short*)(ws + 131072);
  float* b2p   = (float*)(ws + 196608);
  float* b2g   = (float*)(ws + 197632);
  float* gatev = (float*)(ws + 198656);

  float* blended = (float*)d_out;
  float* wout    = blended + (size_t)N * ND;

  som_prep_kernel<<<NC, ND, 0, stream>>>(P, G, gl, Pbf, Gbf, PTbf, b2p, b2g, gatev);
  som_main_kernel<<<N / 128, 256, 0, stream>>>(x, Pbf, Gbf, PTbf, b2p, b2g, gatev,
                                               traw, blended, wout);
}

// Round 2
// 240.710 us; speedup vs baseline: 1.0792x; 1.0792x over previous
//
#include <hip/hip_runtime.h>

typedef short v8s __attribute__((ext_vector_type(8)));
typedef float v4f __attribute__((ext_vector_type(4)));
typedef float f32x16 __attribute__((ext_vector_type(16)));
typedef unsigned int v4u __attribute__((ext_vector_type(4)));

#define NC 256
#define ND 128

__device__ __forceinline__ unsigned short f2bf(float f) {
  union { float f; unsigned int u; } v; v.f = f;
  unsigned int u = v.u;
  unsigned int r = (u + 0x7fffu + ((u >> 16) & 1u)) >> 16;
  return (unsigned short)r;
}

__device__ __forceinline__ unsigned int cvt_pk_bf16(float a, float b) {
  unsigned int r;
  asm("v_cvt_pk_bf16_f32 %0, %1, %2" : "=v"(r) : "v"(a), "v"(b));
  return r;
}

__device__ __forceinline__ void plane32swap(unsigned int &a, unsigned int &b) {
  asm("v_permlane32_swap_b32 %0, %1" : "+v"(a), "+v"(b));
}

// ---------------- prep: fragment-arranged bf16 P/G/PT, norms, gate ----------------
// Distance A-frag (row c, k=d): PbfA[((ct*8+s)*64 + lane)*8 + j] = P[ct*32+(lane&31)][s*16+(lane>>5)*8+j]
// Blend    A-frag (row d, k=c): PTbfA[((dt*16+sc)*64 + lane)*8 + jc] = P[sc*16+(lane>>5)*8+jc][dt*32+(lane&31)]
__global__ void som_prep_kernel(const float* __restrict__ P, const float* __restrict__ G,
                                const float* __restrict__ gate_logits,
                                unsigned short* __restrict__ PbfA, unsigned short* __restrict__ GbfA,
                                unsigned short* __restrict__ PTbfA,
                                float* __restrict__ b2p, float* __restrict__ b2g,
                                float* __restrict__ gatev) {
  int c = blockIdx.x;      // 0..255
  int t = threadIdx.x;     // 0..127 (= d / k index)
  float p = P[c * ND + t];
  float g = G[c * ND + t];

  int ct = c >> 5, l31 = c & 31;
  int s = t >> 4, hia = (t >> 3) & 1, j = t & 7;
  int lane = l31 + 32 * hia;
  PbfA[((ct * 8 + s) * 64 + lane) * 8 + j] = f2bf(p);
  GbfA[((ct * 8 + s) * 64 + lane) * 8 + j] = f2bf(g);

  int dt = t >> 5, l31d = t & 31;
  int sc = c >> 4, hic = (c >> 3) & 1, jc = c & 7;
  int laned = l31d + 32 * hic;
  PTbfA[((dt * 16 + sc) * 64 + laned) * 8 + jc] = f2bf(p);

  float pp = p * p, gg = g * g;
  #pragma unroll
  for (int m = 1; m < 64; m <<= 1) { pp += __shfl_xor(pp, m); gg += __shfl_xor(gg, m); }
  __shared__ float sp[2], sg[2];
  if ((t & 63) == 0) { sp[t >> 6] = pp; sg[t >> 6] = gg; }
  __syncthreads();
  if (t == 0) {
    b2p[c] = sp[0] + sp[1];
    b2g[c] = sg[0] + sg[1];
    gatev[c] = 1.f / (1.f + expf(-gate_logits[c]));
  }
}

// ---------------- main fused kernel ----------------
// 1 wave = 32 x-rows. 32x32x16 MFMA, no LDS.
// S^T = P(32c x 16k) * X^T(16k x 32m): D col = m = lane&31, row c = ct*32+(r&3)+8*(r>>2)+4*hi.
__global__ __launch_bounds__(256, 3) void som_main_kernel(
    const float* __restrict__ x,
    const unsigned short* __restrict__ PbfA,
    const unsigned short* __restrict__ GbfA,
    const unsigned short* __restrict__ PTbfA,
    const float* __restrict__ b2p,
    const float* __restrict__ b2g,
    const float* __restrict__ gatev,
    const float* __restrict__ temp_raw,
    float* __restrict__ blended_out,
    float* __restrict__ w_out)
{
  const int tid  = threadIdx.x;
  const int wid  = tid >> 6;
  const int lane = tid & 63;
  const int l31  = lane & 31;
  const int hi   = lane >> 5;
  const long long R = ((long long)blockIdx.x * 4 + wid) * 32;

  float traw = temp_raw[0];
  float sgm = 1.f / (1.f + __builtin_amdgcn_exp2f(-traw * 1.44269504f));
  float T = sgm * (1.f - 1e-3f) + 1e-3f;
  float k2 = 1.44269504f / T;                 // e = exp2(-d * k2)

  // ---- X B-fragments (col m = l31, k-chunk hi*8) + exact f32 row norm ----
  const float* xr = x + (R + l31) * ND + hi * 8;
  v8s xb[8];
  float a2 = 0.f;
  #pragma unroll
  for (int s = 0; s < 8; ++s) {
    v4f lo  = *(const v4f*)(xr + s * 16);
    v4f hi4 = *(const v4f*)(xr + s * 16 + 4);
    v4u w;
    w[0] = cvt_pk_bf16(lo[0], lo[1]);
    w[1] = cvt_pk_bf16(lo[2], lo[3]);
    w[2] = cvt_pk_bf16(hi4[0], hi4[1]);
    w[3] = cvt_pk_bf16(hi4[2], hi4[3]);
    xb[s] = __builtin_bit_cast(v8s, w);
    #pragma unroll
    for (int j = 0; j < 4; ++j) {
      a2 = fmaf(lo[j], lo[j], a2);
      a2 = fmaf(hi4[j], hi4[j], a2);
    }
  }
  a2 += __shfl_xor(a2, 32);

  // ---- distances + single-pass softmax stats; u = bf16(e*gate) packed ----
  unsigned int u[64];
  float s1 = 0.f, su = 0.f;
  const unsigned short* pb = PbfA + lane * 8;
  const unsigned short* gb = GbfA + lane * 8;
  #pragma unroll
  for (int ct = 0; ct < 8; ++ct) {
    f32x16 aP, aG;
    #pragma unroll
    for (int i = 0; i < 16; ++i) { aP[i] = 0.f; aG[i] = 0.f; }
    #pragma unroll
    for (int s = 0; s < 8; ++s) {
      v8s ap = *(const v8s*)(pb + (ct * 8 + s) * 512);
      v8s ag = *(const v8s*)(gb + (ct * 8 + s) * 512);
      aP = __builtin_amdgcn_mfma_f32_32x32x16_bf16(ap, xb[s], aP, 0, 0, 0);
      aG = __builtin_amdgcn_mfma_f32_32x32x16_bf16(ag, xb[s], aG, 0, 0, 0);
    }
    #pragma unroll
    for (int q = 0; q < 4; ++q) {
      int c0 = ct * 32 + q * 8 + hi * 4;
      v4f bp = *(const v4f*)(b2p + c0);
      v4f bg = *(const v4f*)(b2g + c0);
      v4f gt = *(const v4f*)(gatev + c0);
      float uf[4];
      #pragma unroll
      for (int j2 = 0; j2 < 4; ++j2) {
        int r = q * 4 + j2;
        float d2a = fmaf(-2.f, aP[r], a2 + bp[j2]);
        float d2b = fmaf(-2.f, aG[r], a2 + bg[j2]);
        float d = __builtin_amdgcn_sqrtf(fmaxf(d2a, 1e-12f))
                + __builtin_amdgcn_sqrtf(fmaxf(d2b, 1e-12f));
        float e = __builtin_amdgcn_exp2f(-d * k2);
        float uu = e * gt[j2];
        s1 += e; su += uu;
        uf[j2] = uu;
      }
      u[ct * 8 + 2 * q]     = cvt_pk_bf16(uf[0], uf[1]);
      u[ct * 8 + 2 * q + 1] = cvt_pk_bf16(uf[2], uf[3]);
    }
  }
  s1 += __shfl_xor(s1, 32);
  su += __shfl_xor(su, 32);
  // w = e*gate / (su + eps*(s1+eps))  — exact algebra of the double normalization
  float scale = 1.f / (su + 1e-8f * (s1 + 1e-8f));

  // ---- w out: unpack bf16 u, scale, coalesced-quad stores ----
  float* wbase = w_out + (R + l31) * NC + hi * 4;
  #pragma unroll
  for (int ct = 0; ct < 8; ++ct) {
    #pragma unroll
    for (int q = 0; q < 4; ++q) {
      unsigned int ua = u[ct * 8 + 2 * q], ub = u[ct * 8 + 2 * q + 1];
      v4f wv;
      wv[0] = __uint_as_float(ua << 16) * scale;
      wv[1] = __uint_as_float(ua & 0xffff0000u) * scale;
      wv[2] = __uint_as_float(ub << 16) * scale;
      wv[3] = __uint_as_float(ub & 0xffff0000u) * scale;
      *(v4f*)(wbase + ct * 32 + q * 8) = wv;
    }
  }

  // ---- blended^T = P^T(32d x 16c) * W^T(16c x 32m); W^T via permlane32_swap ----
  f32x16 acc[4];
  #pragma unroll
  for (int dt = 0; dt < 4; ++dt)
    #pragma unroll
    for (int i = 0; i < 16; ++i) acc[dt][i] = 0.f;

  const unsigned short* tb = PTbfA + lane * 8;
  #pragma unroll
  for (int s2 = 0; s2 < 16; ++s2) {
    unsigned int p0 = u[4 * s2], p1 = u[4 * s2 + 1], p2 = u[4 * s2 + 2], p3 = u[4 * s2 + 3];
    plane32swap(p0, p2);     // p0 <- (own lo, partner lo) = b0 ; p2 = b2
    plane32swap(p1, p3);     // p1 = b1 ; p3 = b3
    v4u bw; bw[0] = p0; bw[1] = p1; bw[2] = p2; bw[3] = p3;
    v8s bfrag = __builtin_bit_cast(v8s, bw);
    #pragma unroll
    for (int dt = 0; dt < 4; ++dt) {
      v8s pa = *(const v8s*)(tb + (dt * 16 + s2) * 512);
      acc[dt] = __builtin_amdgcn_mfma_f32_32x32x16_bf16(pa, bfrag, acc[dt], 0, 0, 0);
    }
  }

  float* bbase = blended_out + (R + l31) * ND + hi * 4;
  #pragma unroll
  for (int dt = 0; dt < 4; ++dt) {
    #pragma unroll
    for (int q = 0; q < 4; ++q) {
      v4f ov;
      ov[0] = acc[dt][4 * q + 0] * scale;
      ov[1] = acc[dt][4 * q + 1] * scale;
      ov[2] = acc[dt][4 * q + 2] * scale;
      ov[3] = acc[dt][4 * q + 3] * scale;
      *(v4f*)(bbase + dt * 32 + q * 8) = ov;
    }
  }
}

extern "C" void kernel_launch(void* const* d_in, const int* in_sizes, int n_in,
                              void* d_out, int out_size, void* d_ws, size_t ws_size,
                              hipStream_t stream) {
  const float* x    = (const float*)d_in[0];
  const float* P    = (const float*)d_in[1];
  const float* G    = (const float*)d_in[2];
  const float* traw = (const float*)d_in[3];
  const float* gl   = (const float*)d_in[4];
  const int N = in_sizes[0] / ND;             // 262144

  char* ws = (char*)d_ws;
  unsigned short* PbfA  = (unsigned short*)(ws);
  unsigned short* GbfA  = (unsigned short*)(ws + 65536);
  unsigned short* PTbfA = (unsigned short*)(ws + 131072);
  float* b2p   = (float*)(ws + 196608);
  float* b2g   = (float*)(ws + 197632);
  float* gatev = (float*)(ws + 198656);

  float* blended = (float*)d_out;
  float* wout    = blended + (size_t)N * ND;

  som_prep_kernel<<<NC, ND, 0, stream>>>(P, G, gl, PbfA, GbfA, PTbfA, b2p, b2g, gatev);
  som_main_kernel<<<N / 128, 256, 0, stream>>>(x, PbfA, GbfA, PTbfA, b2p, b2g, gatev,
                                               traw, blended, wout);
}